// Round 7
// baseline (157.973 us; speedup 1.0000x reference)
//
#include <hip/hip_runtime.h>
#include <math.h>

#define BT 256   // 4 waves; each wave = 32 batch elements

typedef _Float16 half2v __attribute__((ext_vector_type(2)));
typedef __fp16   fp16x2 __attribute__((ext_vector_type(2)));
typedef _Float16 half8  __attribute__((ext_vector_type(8)));
typedef float    f32x16 __attribute__((ext_vector_type(16)));

union U4H8 { unsigned int u[4]; half8 h; };

__device__ __forceinline__ half2v u2h(unsigned int u){
  union { unsigned int u; half2v h; } c; c.u = u; return c.h;
}
__device__ __forceinline__ unsigned int h2u(half2v h){
  union { unsigned int u; half2v h; } c; c.h = h; return c.u;
}
__device__ __forceinline__ half2v pkrtz(float a, float b){
  union { fp16x2 f; half2v h; } c;
  c.f = __builtin_amdgcn_cvt_pkrtz(a, b);
  return c.h;
}
__device__ __forceinline__ float fdot2(half2v a, half2v b, float c){
  return __builtin_amdgcn_fdot2(a, b, c, false);
}
__device__ __forceinline__ float frcp(float x){ return __builtin_amdgcn_rcpf(x); }

__device__ __forceinline__ unsigned int pk_rne(float a, float b){
  half2v h; h.x = (_Float16)a; h.y = (_Float16)b; return h2u(h);
}

// f32 exp-based gelu (decode only, 5/lane) — A&S 7.1.25 erf, |eps|<=2.5e-5
__device__ __forceinline__ float gelu_erf(float v){
  float z  = v * 0.70710678118654752f;
  float az = fabsf(z);
  float t  = frcp(fmaf(0.47047f, az, 1.0f));
  float poly = t*fmaf(t, fmaf(t, 0.7478556f, -0.0958798f), 0.3480242f);
  float ex = __expf(-az*az);
  float erfv = fmaf(-poly, ex, 1.0f);
  erfv = (z < 0.0f) ? -erfv : erfv;
  return 0.5f*v*(1.0f + erfv);
}

// tanh via Lambert continued-fraction Pade(5,4): x(t^2+105t+945)/(15t^2+420t+945).
// |err| < 1e-5 for |x|<=2, <=4e-4 at the |x|=3 clamp (pre-acts here are <~1 at 6sigma).
__device__ __forceinline__ float tanh_pade(float x){
  x = fminf(3.0f, fmaxf(-3.0f, x));
  float t = x*x;
  float n = fmaf(t + 105.0f, t, 945.0f);
  float d = fmaf(fmaf(15.0f, t, 420.0f), t, 945.0f);
  return x*n*frcp(d);
}

// packed-f16 gelu: gelu(x) = x*S, S = clamp(0.5 + x*q(x^2), 0, 1);
// q deg-4 Newton fit on t in [0,4]; |gelu err| <= 2.3e-4 on |x|<=2.
__device__ __forceinline__ half2v gelu_pk(half2v x){
  const _Float16 a0 = (_Float16)0.3989423f,  a1 = (_Float16)-0.0663157f,
                 a2 = (_Float16)0.0096298f,  a3 = (_Float16)-0.00095967f,
                 a4 = (_Float16)0.000048f,   hp = (_Float16)0.5f,
                 hn = (_Float16)-0.5f;
  const half2v A0={a0,a0}, A1={a1,a1}, A2={a2,a2}, A3={a3,a3}, A4={a4,a4};
  const half2v HP={hp,hp}, HN={hn,hn};
  half2v t = x*x;
  half2v q = A4*t + A3;
  q = q*t + A2;
  q = q*t + A1;
  q = q*t + A0;
  half2v u = x*q;
#if __has_builtin(__builtin_elementwise_min)
  u = __builtin_elementwise_max(u, HN);
  u = __builtin_elementwise_min(u, HP);
#else
  u.x = u.x > hp ? hp : (u.x < hn ? hn : u.x);
  u.y = u.y > hp ? hp : (u.y < hn ? hn : u.y);
#endif
  return x*(u + HP);
}

// ---------------- ws layout (u32 words) ----------------
// sigma-permuted column storage (pair j of a row holds original cols c0,c0+1,
// c0 = 16*(j>>3) + 8*((j>>1)&1) + 4*((j>>2)&1) + 2*(j&1)) so that the packed
// C/D-layout pair array of the previous MFMA is directly the B-fragment.
//  [0,512)     A_pk   : A = Wq^T Wk               [32][16] pairs, perm cols
//  [512,1024)  M_pk   : M = W_ih*OP*WV            perm cols
//  [1024,1536) W_pk   : whh                       perm cols
//  [1536,2048) D_pk   : rows 0-4 = decw, else 0   perm cols
//  [2048,2304) emb_pk : [32][8] pairs, k<5 = embw, else 0 (natural order)
//  [2304,2320) wv_pk  : wvec = Wk^T bq, [grp][8] row-pair order
//  [2320,2352) bM_f   : f32, bM = W_ih*(OP bv + opb) + b_ih + b_hh (natural)
__global__ void prep_kernel(const float* __restrict__ inw, const float* __restrict__ inb,
                            const float* __restrict__ opw, const float* __restrict__ opb,
                            const float* __restrict__ wih, const float* __restrict__ bih,
                            const float* __restrict__ bhh, const float* __restrict__ whh,
                            const float* __restrict__ decw, const float* __restrict__ embw,
                            unsigned int* __restrict__ wsu){
  __shared__ float sA[1024], sP[1024], sM[1024], sT[32], sWV[32];
  int tx = threadIdx.x & 31;
  int ty = threadIdx.x >> 5;
  float accA = 0.f, accP = 0.f;
  #pragma unroll
  for (int m = 0; m < 32; m++){
    accA += inw[m*32 + ty] * inw[1024 + m*32 + tx];   // Wq[m,ty]*Wk[m,tx]
    accP += opw[ty*32 + m] * inw[2048 + m*32 + tx];   // OP[ty,m]*WV[m,tx]
  }
  sA[ty*32 + tx] = accA;
  sP[ty*32 + tx] = accP;
  if (ty == 0){
    float aw = 0.f;
    #pragma unroll
    for (int m = 0; m < 32; m++) aw += inb[m] * inw[1024 + m*32 + tx];
    sWV[tx] = aw;
  }
  if (ty == 1){
    float at = opb[tx];
    #pragma unroll
    for (int m = 0; m < 32; m++) at += opw[tx*32 + m] * inb[64 + m];
    sT[tx] = at;
  }
  __syncthreads();
  float accM = 0.f;
  #pragma unroll
  for (int m = 0; m < 32; m++) accM += wih[ty*32 + m] * sP[m*32 + tx];
  sM[ty*32 + tx] = accM;
  if (ty == 2){
    float ab = bih[tx] + bhh[tx];
    #pragma unroll
    for (int m = 0; m < 32; m++) ab += wih[tx*32 + m] * sT[m];
    ((float*)wsu)[2320 + tx] = ab;
  }
  __syncthreads();
  int t = threadIdx.x;
  if (t < 512){
    int r = t >> 4, j = t & 15;
    int c0 = 16*(j>>3) + 8*((j>>1)&1) + 4*((j>>2)&1) + 2*(j&1);   // sigma-perm
    wsu[t]        = pk_rne(sA[r*32+c0],  sA[r*32+c0+1]);
    wsu[512 + t]  = pk_rne(sM[r*32+c0],  sM[r*32+c0+1]);
    wsu[1024 + t] = pk_rne(whh[r*32+c0], whh[r*32+c0+1]);
    wsu[1536 + t] = (r < 5) ? pk_rne(decw[r*32+c0], decw[r*32+c0+1]) : 0u;
  } else if (t < 768){                     // emb_pk: [32][8] pairs, natural
    int q = t - 512, j2 = q >> 3, cc = (q & 7)*2;
    float a = (cc   < 5) ? embw[j2*5+cc]   : 0.f;
    float b = (cc+1 < 5) ? embw[j2*5+cc+1] : 0.f;
    wsu[2048 + q] = pk_rne(a, b);
  } else if (t < 784){                     // wv_pk in C/D row-pair order
    int q = t - 768, gg = q >> 3, j = q & 7;
    int r0 = 2*(j&1) + 8*(j>>1) + 4*gg;
    wsu[2304 + q] = pk_rne(sWV[r0], sWV[r0+1]);
  }
}

__device__ __forceinline__ half8 ldfrag(const unsigned int* __restrict__ p){
  U4H8 t; t.u[0]=p[0]; t.u[1]=p[1]; t.u[2]=p[2]; t.u[3]=p[3]; return t.h;
}
__device__ __forceinline__ half8 h8of(const unsigned int* q){
  U4H8 t; t.u[0]=q[0]; t.u[1]=q[1]; t.u[2]=q[2]; t.u[3]=q[3]; return t.h;
}

// load 16 f32 bias values for this lane's C-frag rows via 4x float4
__device__ __forceinline__ f32x16 ldbias(const float* __restrict__ p, int grp){
  const float4* b = (const float4*)(p + 4*grp);
  float4 q0 = b[0], q1 = b[2], q2 = b[4], q3 = b[6];
  f32x16 c;
  c[0]=q0.x; c[1]=q0.y; c[2]=q0.z; c[3]=q0.w;
  c[4]=q1.x; c[5]=q1.y; c[6]=q1.z; c[7]=q1.w;
  c[8]=q2.x; c[9]=q2.y; c[10]=q2.z; c[11]=q2.w;
  c[12]=q3.x; c[13]=q3.y; c[14]=q3.z; c[15]=q3.w;
  return c;
}

__global__ __launch_bounds__(BT) void fused_kernel(
    const float* __restrict__ x,
    const unsigned int* __restrict__ wsu,
    const float* __restrict__ embb,
    const float* __restrict__ decb,
    const float* __restrict__ outw, const float* __restrict__ outb,
    float* __restrict__ y, int B)
{
  int tid  = threadIdx.x;
  int lane = tid & 63;
  int col  = lane & 31;
  bool g   = (lane >> 5) != 0;
  int grp  = g ? 1 : 0;
  long long base = ((long long)blockIdx.x*(BT/64) + (tid>>6)) * 32;
  if (base >= B) return;
  long long elem = base + col;

  const unsigned int* pA = wsu;
  const unsigned int* pM = wsu + 512;
  const unsigned int* pW = wsu + 1024;
  const unsigned int* pD = wsu + 1536;
  const unsigned int* pE = wsu + 2048;
  const unsigned int* pwv = wsu + 2304;
  const float* bMf = (const float*)(wsu + 2320);

  half8 embA = ldfrag(pE + col*8  + grp*4);
  half8 A1   = ldfrag(pA + col*16 + grp*4), A2 = ldfrag(pA + col*16 + 8 + grp*4);
  half8 M1   = ldfrag(pM + col*16 + grp*4), M2 = ldfrag(pM + col*16 + 8 + grp*4);
  half8 W1   = ldfrag(pW + col*16 + grp*4), W2 = ldfrag(pW + col*16 + 8 + grp*4);
  half8 D1   = ldfrag(pD + col*16 + grp*4), D2 = ldfrag(pD + col*16 + 8 + grp*4);
  half2v wv[8];
  #pragma unroll
  for (int j = 0; j < 8; j++) wv[j] = u2h(pwv[grp*8 + j]);

  f32x16 cb_emb = ldbias(embb, grp);
  f32x16 cb_bM  = ldbias(bMf,  grp);

  // ---- x load + B-frags (k0-4 = x, rest 0; group1 all 0) ----
  const float2* xp = (const float2*)(x + elem*10ll);
  float2 p0 = xp[0], p1 = xp[1], p2 = xp[2], p3 = xp[3], p4 = xp[4];
  U4H8 xb0, xb1;
  xb0.u[0] = g ? 0u : h2u(pkrtz(p0.x, p0.y));
  xb0.u[1] = g ? 0u : h2u(pkrtz(p1.x, p1.y));
  xb0.u[2] = g ? 0u : h2u(pkrtz(p2.x, 0.f));
  xb0.u[3] = 0u;
  xb1.u[0] = g ? 0u : h2u(pkrtz(p2.y, p3.x));
  xb1.u[1] = g ? 0u : h2u(pkrtz(p3.y, p4.x));
  xb1.u[2] = g ? 0u : h2u(pkrtz(p4.y, 0.f));
  xb1.u[3] = 0u;

  // ---- embedding (bias via C) + packed-f16 gelu; pairs ARE next B-frags ----
  f32x16 e0D = __builtin_amdgcn_mfma_f32_32x32x16_f16(embA, xb0.h, cb_emb, 0,0,0);
  f32x16 e1D = __builtin_amdgcn_mfma_f32_32x32x16_f16(embA, xb1.h, cb_emb, 0,0,0);
  unsigned int epk[8], dlpk[8];
  #pragma unroll
  for (int i = 0; i < 8; i++){
    half2v e0h = gelu_pk(pkrtz(e0D[2*i], e0D[2*i+1]));
    half2v e1h = gelu_pk(pkrtz(e1D[2*i], e1D[2*i+1]));
    epk[i]  = h2u(e0h);
    dlpk[i] = h2u(e1h - e0h);
  }

  // ---- score: g = A*delta (sigma-permuted A -> dlpk is the B-frag) ----
  f32x16 z16;
  #pragma unroll
  for (int i = 0; i < 16; i++) z16[i] = 0.f;
  f32x16 gD = __builtin_amdgcn_mfma_f32_32x32x16_f16(A1, h8of(dlpk), z16, 0,0,0);
  gD = __builtin_amdgcn_mfma_f32_32x32x16_f16(A2, h8of(dlpk+4), gD, 0,0,0);

  float t0 = 0.f, t1 = 0.f, dw = 0.f;
  #pragma unroll
  for (int i = 0; i < 8; i++){
    half2v gp = pkrtz(gD[2*i], gD[2*i+1]);
    t0 = fdot2(u2h(epk[i]),  gp, t0);
    t1 = fdot2(u2h(dlpk[i]), gp, t1);
    dw = fdot2(wv[i], u2h(dlpk[i]), dw);
  }
  t0 += __shfl_xor(t0, 32);
  t1 += __shfl_xor(t1, 32);
  dw += __shfl_xor(dw, 32);

  const float iss = 0.17677669529663689f;   // 1/sqrt(32)
  float a01 = frcp(1.0f + __expf(-((t0      + dw)*iss)));
  float a11 = frcp(1.0f + __expf(-((t0 + t1 + dw)*iss)));

  // ---- c0 = e0 + a01*delta; c1 = c0 + (a11-a01)*delta (packed, in-layout) ----
  _Float16 q01 = (_Float16)a01, qda = (_Float16)(a11 - a01);
  half2v s01 = {q01,q01}, sda = {qda,qda};
  unsigned int c0pk[8], c1pk[8];
  #pragma unroll
  for (int j = 0; j < 8; j++){
    half2v c0 = u2h(dlpk[j])*s01 + u2h(epk[j]);
    half2v c1 = u2h(dlpk[j])*sda + c0;
    c0pk[j] = h2u(c0); c1pk[j] = h2u(c1);
  }

  // ---- h1 = tanh(M c0 + bM) ----
  f32x16 h1D = __builtin_amdgcn_mfma_f32_32x32x16_f16(M1, h8of(c0pk), cb_bM, 0,0,0);
  h1D = __builtin_amdgcn_mfma_f32_32x32x16_f16(M2, h8of(c0pk+4), h1D, 0,0,0);
  unsigned int h1pk[8];
  #pragma unroll
  for (int i = 0; i < 8; i++)
    h1pk[i] = h2u(pkrtz(tanh_pade(h1D[2*i]), tanh_pade(h1D[2*i+1])));

  // ---- h2 = tanh(M c1 + Whh h1 + bM) ----
  f32x16 h2D = __builtin_amdgcn_mfma_f32_32x32x16_f16(M1, h8of(c1pk), cb_bM, 0,0,0);
  h2D = __builtin_amdgcn_mfma_f32_32x32x16_f16(M2, h8of(c1pk+4), h2D, 0,0,0);
  h2D = __builtin_amdgcn_mfma_f32_32x32x16_f16(W1, h8of(h1pk),   h2D, 0,0,0);
  h2D = __builtin_amdgcn_mfma_f32_32x32x16_f16(W2, h8of(h1pk+4), h2D, 0,0,0);
  unsigned int h2pk[8];
  #pragma unroll
  for (int i = 0; i < 8; i++)
    h2pk[i] = h2u(pkrtz(tanh_pade(h2D[2*i]), tanh_pade(h2D[2*i+1])));

  // ---- decode (bias as wave-uniform scalar adds) ----
  f32x16 dvD = __builtin_amdgcn_mfma_f32_32x32x16_f16(D1, h8of(h2pk), z16, 0,0,0);
  dvD = __builtin_amdgcn_mfma_f32_32x32x16_f16(D2, h8of(h2pk+4), dvD, 0,0,0);
  float dv4 = __shfl_xor(dvD[0], 32);   // grp1 reg0 = row 4

  float d0 = gelu_erf(dvD[0] + decb[0]);
  float d1 = gelu_erf(dvD[1] + decb[1]);
  float d2 = gelu_erf(dvD[2] + decb[2]);
  float d3 = gelu_erf(dvD[3] + decb[3]);
  float d4 = gelu_erf(dv4    + decb[4]);
  float y0 = outb[0] + outw[0]*d0 + outw[1]*d1 + outw[2]*d2 + outw[3]*d3 + outw[4]*d4;
  float y1 = outb[1] + outw[5]*d0 + outw[6]*d1 + outw[7]*d2 + outw[8]*d3 + outw[9]*d4;
  float y2 = outb[2] + outw[10]*d0 + outw[11]*d1 + outw[12]*d2 + outw[13]*d3 + outw[14]*d4;
  if (lane < 32){
    float* yp = y + elem*3ll;
    yp[0] = y0; yp[1] = y1; yp[2] = y2;
  }
}

extern "C" void kernel_launch(void* const* d_in, const int* in_sizes, int n_in,
                              void* d_out, int out_size, void* d_ws, size_t ws_size,
                              hipStream_t stream){
  const float* x    = (const float*)d_in[0];
  const float* embw = (const float*)d_in[1];
  const float* embb = (const float*)d_in[2];
  const float* inw  = (const float*)d_in[3];
  const float* inb  = (const float*)d_in[4];
  const float* opw  = (const float*)d_in[5];
  const float* opb  = (const float*)d_in[6];
  const float* wih  = (const float*)d_in[7];
  const float* bih  = (const float*)d_in[8];
  const float* whh  = (const float*)d_in[9];
  const float* bhh  = (const float*)d_in[10];
  const float* decw = (const float*)d_in[11];
  const float* decb = (const float*)d_in[12];
  const float* outw = (const float*)d_in[13];
  const float* outb = (const float*)d_in[14];
  float* y = (float*)d_out;
  unsigned int* wsu = (unsigned int*)d_ws;   // 2352 u32 = 9.4 KB

  int B = in_sizes[0] / 10;                  // [B,2,5]
  int elems_per_block = (BT/64)*32;          // 128

  prep_kernel<<<1, 1024, 0, stream>>>(inw, inb, opw, opb, wih, bih, bhh,
                                      whh, decw, embw, wsu);
  fused_kernel<<<(B + elems_per_block - 1)/elems_per_block, BT, 0, stream>>>(
      x, wsu, embb, decb, outw, outb, y, B);
}

// Round 8
// 144.912 us; speedup vs baseline: 1.0901x; 1.0901x over previous
//
#include <hip/hip_runtime.h>
#include <math.h>

#define BT 256   // 4 waves; each wave = 32 batch elements

typedef _Float16 half2v __attribute__((ext_vector_type(2)));
typedef __fp16   fp16x2 __attribute__((ext_vector_type(2)));
typedef _Float16 half8  __attribute__((ext_vector_type(8)));
typedef float    f32x16 __attribute__((ext_vector_type(16)));

union U4H8 { unsigned int u[4]; half8 h; };

__device__ __forceinline__ half2v u2h(unsigned int u){
  union { unsigned int u; half2v h; } c; c.u = u; return c.h;
}
__device__ __forceinline__ unsigned int h2u(half2v h){
  union { unsigned int u; half2v h; } c; c.h = h; return c.u;
}
__device__ __forceinline__ half2v pkrtz(float a, float b){
  union { fp16x2 f; half2v h; } c;
  c.f = __builtin_amdgcn_cvt_pkrtz(a, b);
  return c.h;
}
__device__ __forceinline__ float fdot2(half2v a, half2v b, float c){
  return __builtin_amdgcn_fdot2(a, b, c, false);
}
__device__ __forceinline__ float frcp(float x){ return __builtin_amdgcn_rcpf(x); }

__device__ __forceinline__ unsigned int pk_rne(float a, float b){
  half2v h; h.x = (_Float16)a; h.y = (_Float16)b; return h2u(h);
}

// packed-f16 gelu: gelu(x) = x*S, S = clamp(0.5 + x*q(x^2), 0, 1);
// q deg-4 fit on t in [0,4]; |gelu err| <= 2.3e-4 on |x|<=2, correct asymptote beyond.
__device__ __forceinline__ half2v gelu_pk(half2v x){
  const _Float16 a0 = (_Float16)0.3989423f,  a1 = (_Float16)-0.0663157f,
                 a2 = (_Float16)0.0096298f,  a3 = (_Float16)-0.00095967f,
                 a4 = (_Float16)0.000048f,   hp = (_Float16)0.5f,
                 hn = (_Float16)-0.5f;
  const half2v A0={a0,a0}, A1={a1,a1}, A2={a2,a2}, A3={a3,a3}, A4={a4,a4};
  const half2v HP={hp,hp}, HN={hn,hn};
  half2v t = x*x;
  half2v q = A4*t + A3;
  q = q*t + A2;
  q = q*t + A1;
  q = q*t + A0;
  half2v u = x*q;
#if __has_builtin(__builtin_elementwise_min)
  u = __builtin_elementwise_max(u, HN);
  u = __builtin_elementwise_min(u, HP);
#else
  u.x = u.x > hp ? hp : (u.x < hn ? hn : u.x);
  u.y = u.y > hp ? hp : (u.y < hn ? hn : u.y);
#endif
  return x*(u + HP);
}

// packed-f16 tanh: clamp to +-2, then x*P(x^2); P = deg-5 Chebyshev-node fit of
// tanh(sqrt(t))/sqrt(t) on t in [0,4] (max err ~3e-4 in P, ~5e-4 on tanh incl f16).
// Pre-acts here are sigma~0.25, so |x|>2 is ~8-sigma — clamp never bites in practice.
__device__ __forceinline__ half2v tanh_pk(half2v x){
  const _Float16 c0=(_Float16)0.999716f,  c1=(_Float16)-0.328107f,
                 c2=(_Float16)0.116352f,  c3=(_Float16)-0.031255f,
                 c4=(_Float16)0.005038f,  c5=(_Float16)-0.000348f,
                 tp=(_Float16)2.0f,       tn=(_Float16)-2.0f;
  const half2v C0={c0,c0},C1={c1,c1},C2={c2,c2},C3={c3,c3},C4={c4,c4},C5={c5,c5};
  const half2v TP={tp,tp}, TN={tn,tn};
#if __has_builtin(__builtin_elementwise_min)
  x = __builtin_elementwise_max(x, TN);
  x = __builtin_elementwise_min(x, TP);
#else
  x.x = x.x > tp ? tp : (x.x < tn ? tn : x.x);
  x.y = x.y > tp ? tp : (x.y < tn ? tn : x.y);
#endif
  half2v t = x*x;
  half2v p = C5*t + C4;
  p = p*t + C3;
  p = p*t + C2;
  p = p*t + C1;
  p = p*t + C0;
  return x*p;
}

// ---------------- ws layout (u32 words) ----------------
// sigma-permuted column storage (pair j of a row holds original cols c0,c0+1,
// c0 = 16*(j>>3) + 8*((j>>1)&1) + 4*((j>>2)&1) + 2*(j&1)) so the packed C/D
// pair array of the previous MFMA is directly the next B-fragment.
//  [0,512)     A_pk   : iss * Wq^T Wk            [32][16] pairs, perm cols
//  [512,1024)  M_pk   : M = W_ih*OP*WV           perm cols
//  [1024,1536) W_pk   : whh                      perm cols
//  [1536,2048) D_pk   : rows 0-4 = decw, else 0  perm cols
//  [2048,2304) emb_pk : [32][8] pairs, k<5 = embw, else 0 (natural)
//  [2304,2320) wv_pk  : iss * Wk^T bq, [grp][8] C/D row-pair order
//  [2320,2352) bM_f   : f32, bM = W_ih*(OP bv + opb) + b_ih + b_hh (natural)
//  [2352,2355) decb_pk: (b0,b1),(b2,b3),(b4,0)
//  [2355,2364) out_pk : row r: (w0,w1),(w2,w3),(w4,0)
__global__ void prep_kernel(const float* __restrict__ inw, const float* __restrict__ inb,
                            const float* __restrict__ opw, const float* __restrict__ opb,
                            const float* __restrict__ wih, const float* __restrict__ bih,
                            const float* __restrict__ bhh, const float* __restrict__ whh,
                            const float* __restrict__ decw, const float* __restrict__ embw,
                            const float* __restrict__ decb, const float* __restrict__ outw,
                            unsigned int* __restrict__ wsu){
  __shared__ float sQ[1024], sK[1024], sV[1024], sOP[1024], sWI[1024];
  __shared__ float sA[1024], sP[1024], sM[1024], sT[32], sWV[32];
  const float ISS = 0.17677669529663689f;   // 1/sqrt(32)
  int t = threadIdx.x;
  // coalesced stage of all 32x32 operands into LDS
  sQ[t]  = inw[t];
  sK[t]  = inw[1024 + t];
  sV[t]  = inw[2048 + t];
  sOP[t] = opw[t];
  sWI[t] = wih[t];
  __syncthreads();
  int tx = t & 31, ty = t >> 5;
  float accA = 0.f, accP = 0.f;
  #pragma unroll
  for (int m = 0; m < 32; m++){
    accA += sQ[m*32 + ty] * sK[m*32 + tx];    // Wq[m,ty]*Wk[m,tx]
    accP += sOP[ty*32 + m] * sV[m*32 + tx];   // OP[ty,m]*WV[m,tx]
  }
  sA[ty*32 + tx] = accA;
  sP[ty*32 + tx] = accP;
  if (ty == 0){
    float aw = 0.f;
    #pragma unroll
    for (int m = 0; m < 32; m++) aw += inb[m] * sK[m*32 + tx];   // bq[m]*Wk[m,tx]
    sWV[tx] = aw;
  }
  if (ty == 1){
    float at = opb[tx];
    #pragma unroll
    for (int m = 0; m < 32; m++) at += sOP[tx*32 + m] * inb[64 + m];  // OP[tx,m]*bv[m]
    sT[tx] = at;
  }
  __syncthreads();
  float accM = 0.f;
  #pragma unroll
  for (int m = 0; m < 32; m++) accM += sWI[ty*32 + m] * sP[m*32 + tx];
  sM[ty*32 + tx] = accM;
  if (ty == 2){
    float ab = bih[tx] + bhh[tx];
    #pragma unroll
    for (int m = 0; m < 32; m++) ab += sWI[tx*32 + m] * sT[m];
    ((float*)wsu)[2320 + tx] = ab;
  }
  __syncthreads();
  if (t < 512){
    int r = t >> 4, j = t & 15;
    int c0 = 16*(j>>3) + 8*((j>>1)&1) + 4*((j>>2)&1) + 2*(j&1);   // sigma-perm
    wsu[t]        = pk_rne(ISS*sA[r*32+c0], ISS*sA[r*32+c0+1]);
    wsu[512 + t]  = pk_rne(sM[r*32+c0],  sM[r*32+c0+1]);
    wsu[1024 + t] = pk_rne(whh[r*32+c0], whh[r*32+c0+1]);
    wsu[1536 + t] = (r < 5) ? pk_rne(decw[r*32+c0], decw[r*32+c0+1]) : 0u;
  } else if (t < 768){                     // emb_pk: [32][8] pairs, natural
    int q = t - 512, j2 = q >> 3, cc = (q & 7)*2;
    float a = (cc   < 5) ? embw[j2*5+cc]   : 0.f;
    float b = (cc+1 < 5) ? embw[j2*5+cc+1] : 0.f;
    wsu[2048 + q] = pk_rne(a, b);
  } else if (t < 784){                     // wv_pk in C/D row-pair order, iss-scaled
    int q = t - 768, gg = q >> 3, j = q & 7;
    int r0 = 2*(j&1) + 8*(j>>1) + 4*gg;
    wsu[2304 + q] = pk_rne(ISS*sWV[r0], ISS*sWV[r0+1]);
  } else if (t < 787){                     // decb_pk
    int i = t - 784, c = 2*i;
    float a = decb[c];
    float b = (c+1 < 5) ? decb[c+1] : 0.f;
    wsu[2352 + i] = pk_rne(a, b);
  } else if (t < 796){                     // out_pk: 3 rows x 3 pairs
    int q = t - 787;
    int r = (q >= 6) ? 2 : ((q >= 3) ? 1 : 0);
    int p = q - r*3, c = 2*p;
    float a = outw[r*5 + c];
    float b = (c+1 < 5) ? outw[r*5 + c + 1] : 0.f;
    wsu[2355 + q] = pk_rne(a, b);
  }
}

__device__ __forceinline__ half8 ldfrag(const unsigned int* __restrict__ p){
  U4H8 t; t.u[0]=p[0]; t.u[1]=p[1]; t.u[2]=p[2]; t.u[3]=p[3]; return t.h;
}
__device__ __forceinline__ half8 h8of(const unsigned int* q){
  U4H8 t; t.u[0]=q[0]; t.u[1]=q[1]; t.u[2]=q[2]; t.u[3]=q[3]; return t.h;
}

// 16 f32 bias values for this lane's C-frag rows via 4x float4
__device__ __forceinline__ f32x16 ldbias(const float* __restrict__ p, int grp){
  const float4* b = (const float4*)(p + 4*grp);
  float4 q0 = b[0], q1 = b[2], q2 = b[4], q3 = b[6];
  f32x16 c;
  c[0]=q0.x; c[1]=q0.y; c[2]=q0.z; c[3]=q0.w;
  c[4]=q1.x; c[5]=q1.y; c[6]=q1.z; c[7]=q1.w;
  c[8]=q2.x; c[9]=q2.y; c[10]=q2.z; c[11]=q2.w;
  c[12]=q3.x; c[13]=q3.y; c[14]=q3.z; c[15]=q3.w;
  return c;
}

__global__ __launch_bounds__(BT) void fused_kernel(
    const float* __restrict__ x,
    const unsigned int* __restrict__ wsu,
    const float* __restrict__ embb,
    const float* __restrict__ outb,
    float* __restrict__ y, int B)
{
  int tid  = threadIdx.x;
  int lane = tid & 63;
  int col  = lane & 31;
  bool g   = (lane >> 5) != 0;
  int grp  = g ? 1 : 0;
  long long base = ((long long)blockIdx.x*(BT/64) + (tid>>6)) * 32;
  if (base >= B) return;
  long long elem = base + col;

  const unsigned int* pA = wsu;
  const unsigned int* pM = wsu + 512;
  const unsigned int* pW = wsu + 1024;
  const unsigned int* pD = wsu + 1536;
  const unsigned int* pE = wsu + 2048;
  const unsigned int* pwv = wsu + 2304;
  const float* bMf = (const float*)(wsu + 2320);
  const unsigned int* pdb  = wsu + 2352;
  const unsigned int* pout = wsu + 2355;

  half8 embA = ldfrag(pE + col*8  + grp*4);
  half8 A1   = ldfrag(pA + col*16 + grp*4), A2 = ldfrag(pA + col*16 + 8 + grp*4);
  half8 M1   = ldfrag(pM + col*16 + grp*4), M2 = ldfrag(pM + col*16 + 8 + grp*4);
  half8 W1   = ldfrag(pW + col*16 + grp*4), W2 = ldfrag(pW + col*16 + 8 + grp*4);
  half8 D1   = ldfrag(pD + col*16 + grp*4), D2 = ldfrag(pD + col*16 + 8 + grp*4);
  half2v wv[8];
  #pragma unroll
  for (int j = 0; j < 8; j++) wv[j] = u2h(pwv[grp*8 + j]);

  f32x16 cb_emb = ldbias(embb, grp);
  f32x16 cb_bM  = ldbias(bMf,  grp);

  // ---- x load + B-frags (k0-4 = x, rest 0; group1 all 0) ----
  const float2* xp = (const float2*)(x + elem*10ll);
  float2 p0 = xp[0], p1 = xp[1], p2 = xp[2], p3 = xp[3], p4 = xp[4];
  U4H8 xb0, xb1;
  xb0.u[0] = g ? 0u : h2u(pkrtz(p0.x, p0.y));
  xb0.u[1] = g ? 0u : h2u(pkrtz(p1.x, p1.y));
  xb0.u[2] = g ? 0u : h2u(pkrtz(p2.x, 0.f));
  xb0.u[3] = 0u;
  xb1.u[0] = g ? 0u : h2u(pkrtz(p2.y, p3.x));
  xb1.u[1] = g ? 0u : h2u(pkrtz(p3.y, p4.x));
  xb1.u[2] = g ? 0u : h2u(pkrtz(p4.y, 0.f));
  xb1.u[3] = 0u;

  // ---- embedding (bias via C) + packed-f16 gelu; pairs ARE next B-frags ----
  f32x16 e0D = __builtin_amdgcn_mfma_f32_32x32x16_f16(embA, xb0.h, cb_emb, 0,0,0);
  f32x16 e1D = __builtin_amdgcn_mfma_f32_32x32x16_f16(embA, xb1.h, cb_emb, 0,0,0);
  unsigned int epk[8], dlpk[8];
  #pragma unroll
  for (int i = 0; i < 8; i++){
    half2v e0h = gelu_pk(pkrtz(e0D[2*i], e0D[2*i+1]));
    half2v e1h = gelu_pk(pkrtz(e1D[2*i], e1D[2*i+1]));
    epk[i]  = h2u(e0h);
    dlpk[i] = h2u(e1h - e0h);
  }

  // ---- score: g = (iss*A)*delta (sigma-permuted A -> dlpk is the B-frag) ----
  f32x16 z16;
  #pragma unroll
  for (int i = 0; i < 16; i++) z16[i] = 0.f;
  f32x16 gD = __builtin_amdgcn_mfma_f32_32x32x16_f16(A1, h8of(dlpk), z16, 0,0,0);
  gD = __builtin_amdgcn_mfma_f32_32x32x16_f16(A2, h8of(dlpk+4), gD, 0,0,0);

  float t0 = 0.f, t1 = 0.f, dw = 0.f;
  #pragma unroll
  for (int i = 0; i < 8; i++){
    half2v gp = pkrtz(gD[2*i], gD[2*i+1]);
    t0 = fdot2(u2h(epk[i]),  gp, t0);
    t1 = fdot2(u2h(dlpk[i]), gp, t1);
    dw = fdot2(wv[i], u2h(dlpk[i]), dw);
  }
  t0 += __shfl_xor(t0, 32);
  t1 += __shfl_xor(t1, 32);
  dw += __shfl_xor(dw, 32);

  // ---- 2-way softmax on logit differences (iss already folded into A, wv) ----
  float a01 = frcp(1.0f + __expf(-(t0      + dw)));
  float a11 = frcp(1.0f + __expf(-(t0 + t1 + dw)));

  // ---- c0 = e0 + a01*delta; c1 = c0 + (a11-a01)*delta (packed, in-layout) ----
  _Float16 q01 = (_Float16)a01, qda = (_Float16)(a11 - a01);
  half2v s01 = {q01,q01}, sda = {qda,qda};
  unsigned int c0pk[8], c1pk[8];
  #pragma unroll
  for (int j = 0; j < 8; j++){
    half2v c0 = u2h(dlpk[j])*s01 + u2h(epk[j]);
    half2v c1 = u2h(dlpk[j])*sda + c0;
    c0pk[j] = h2u(c0); c1pk[j] = h2u(c1);
  }

  // ---- h1 = tanh(M c0 + bM), packed-f16 tanh ----
  f32x16 h1D = __builtin_amdgcn_mfma_f32_32x32x16_f16(M1, h8of(c0pk), cb_bM, 0,0,0);
  h1D = __builtin_amdgcn_mfma_f32_32x32x16_f16(M2, h8of(c0pk+4), h1D, 0,0,0);
  unsigned int h1pk[8];
  #pragma unroll
  for (int i = 0; i < 8; i++)
    h1pk[i] = h2u(tanh_pk(pkrtz(h1D[2*i], h1D[2*i+1])));

  // ---- h2 = tanh(M c1 + Whh h1 + bM) ----
  f32x16 h2D = __builtin_amdgcn_mfma_f32_32x32x16_f16(M1, h8of(c1pk), cb_bM, 0,0,0);
  h2D = __builtin_amdgcn_mfma_f32_32x32x16_f16(M2, h8of(c1pk+4), h2D, 0,0,0);
  h2D = __builtin_amdgcn_mfma_f32_32x32x16_f16(W1, h8of(h1pk),   h2D, 0,0,0);
  h2D = __builtin_amdgcn_mfma_f32_32x32x16_f16(W2, h8of(h1pk+4), h2D, 0,0,0);
  unsigned int h2pk[8];
  #pragma unroll
  for (int i = 0; i < 8; i++)
    h2pk[i] = h2u(tanh_pk(pkrtz(h2D[2*i], h2D[2*i+1])));

  // ---- decode MFMA; epilogue fully packed f16 ----
  f32x16 dvD = __builtin_amdgcn_mfma_f32_32x32x16_f16(D1, h8of(h2pk), z16, 0,0,0);
  dvD = __builtin_amdgcn_mfma_f32_32x32x16_f16(D2, h8of(h2pk+4), dvD, 0,0,0);
  float dv4 = __shfl_xor(dvD[0], 32);   // grp1 reg0 = row 4

  half2v dp0 = pkrtz(dvD[0], dvD[1]) + u2h(pdb[0]);
  half2v dp1 = pkrtz(dvD[2], dvD[3]) + u2h(pdb[1]);
  half2v dp2 = pkrtz(dv4,    0.f   ) + u2h(pdb[2]);
  dp0 = gelu_pk(dp0); dp1 = gelu_pk(dp1); dp2 = gelu_pk(dp2);

  float y0 = fdot2(u2h(pout[0]), dp0, fdot2(u2h(pout[1]), dp1, fdot2(u2h(pout[2]), dp2, outb[0])));
  float y1 = fdot2(u2h(pout[3]), dp0, fdot2(u2h(pout[4]), dp1, fdot2(u2h(pout[5]), dp2, outb[1])));
  float y2 = fdot2(u2h(pout[6]), dp0, fdot2(u2h(pout[7]), dp1, fdot2(u2h(pout[8]), dp2, outb[2])));
  if (lane < 32){
    float* yp = y + elem*3ll;
    yp[0] = y0; yp[1] = y1; yp[2] = y2;
  }
}

extern "C" void kernel_launch(void* const* d_in, const int* in_sizes, int n_in,
                              void* d_out, int out_size, void* d_ws, size_t ws_size,
                              hipStream_t stream){
  const float* x    = (const float*)d_in[0];
  const float* embw = (const float*)d_in[1];
  const float* embb = (const float*)d_in[2];
  const float* inw  = (const float*)d_in[3];
  const float* inb  = (const float*)d_in[4];
  const float* opw  = (const float*)d_in[5];
  const float* opb  = (const float*)d_in[6];
  const float* wih  = (const float*)d_in[7];
  const float* bih  = (const float*)d_in[8];
  const float* whh  = (const float*)d_in[9];
  const float* bhh  = (const float*)d_in[10];
  const float* decw = (const float*)d_in[11];
  const float* decb = (const float*)d_in[12];
  const float* outw = (const float*)d_in[13];
  const float* outb = (const float*)d_in[14];
  float* y = (float*)d_out;
  unsigned int* wsu = (unsigned int*)d_ws;   // 2364 u32 = 9.5 KB

  int B = in_sizes[0] / 10;                  // [B,2,5]
  int elems_per_block = (BT/64)*32;          // 128

  prep_kernel<<<1, 1024, 0, stream>>>(inw, inb, opw, opb, wih, bih, bhh,
                                      whh, decw, embw, decb, outw, wsu);
  fused_kernel<<<(B + elems_per_block - 1)/elems_per_block, BT, 0, stream>>>(
      x, wsu, embb, outb, y, B);
}

// Round 9
// 137.163 us; speedup vs baseline: 1.1517x; 1.0565x over previous
//
#include <hip/hip_runtime.h>
#include <math.h>

#define BT 256   // 4 waves; each wave = TWO 32-element tiles (64 elems) for ILP

typedef _Float16 half2v __attribute__((ext_vector_type(2)));
typedef __fp16   fp16x2 __attribute__((ext_vector_type(2)));
typedef _Float16 half8  __attribute__((ext_vector_type(8)));
typedef float    f32x16 __attribute__((ext_vector_type(16)));

union U4H8 { unsigned int u[4]; half8 h; };

__device__ __forceinline__ half2v u2h(unsigned int u){
  union { unsigned int u; half2v h; } c; c.u = u; return c.h;
}
__device__ __forceinline__ unsigned int h2u(half2v h){
  union { unsigned int u; half2v h; } c; c.h = h; return c.u;
}
__device__ __forceinline__ half2v pkrtz(float a, float b){
  union { fp16x2 f; half2v h; } c;
  c.f = __builtin_amdgcn_cvt_pkrtz(a, b);
  return c.h;
}
__device__ __forceinline__ float fdot2(half2v a, half2v b, float c){
  return __builtin_amdgcn_fdot2(a, b, c, false);
}
__device__ __forceinline__ float frcp(float x){ return __builtin_amdgcn_rcpf(x); }

__device__ __forceinline__ unsigned int pk_rne(float a, float b){
  half2v h; h.x = (_Float16)a; h.y = (_Float16)b; return h2u(h);
}

// packed-f16 gelu: gelu(x) = x*S, S = clamp(0.5 + x*q(x^2), 0, 1);
// q deg-4 fit on t in [0,4]; |gelu err| <= 2.3e-4 on |x|<=2, correct asymptote beyond.
__device__ __forceinline__ half2v gelu_pk(half2v x){
  const _Float16 a0 = (_Float16)0.3989423f,  a1 = (_Float16)-0.0663157f,
                 a2 = (_Float16)0.0096298f,  a3 = (_Float16)-0.00095967f,
                 a4 = (_Float16)0.000048f,   hp = (_Float16)0.5f,
                 hn = (_Float16)-0.5f;
  const half2v A0={a0,a0}, A1={a1,a1}, A2={a2,a2}, A3={a3,a3}, A4={a4,a4};
  const half2v HP={hp,hp}, HN={hn,hn};
  half2v t = x*x;
  half2v q = A4*t + A3;
  q = q*t + A2;
  q = q*t + A1;
  q = q*t + A0;
  half2v u = x*q;
#if __has_builtin(__builtin_elementwise_min)
  u = __builtin_elementwise_max(u, HN);
  u = __builtin_elementwise_min(u, HP);
#else
  u.x = u.x > hp ? hp : (u.x < hn ? hn : u.x);
  u.y = u.y > hp ? hp : (u.y < hn ? hn : u.y);
#endif
  return x*(u + HP);
}

// packed-f16 tanh: clamp +-2, x*P(x^2), deg-5 fit (|err| ~5e-4 incl f16 rounding).
__device__ __forceinline__ half2v tanh_pk(half2v x){
  const _Float16 c0=(_Float16)0.999716f,  c1=(_Float16)-0.328107f,
                 c2=(_Float16)0.116352f,  c3=(_Float16)-0.031255f,
                 c4=(_Float16)0.005038f,  c5=(_Float16)-0.000348f,
                 tp=(_Float16)2.0f,       tn=(_Float16)-2.0f;
  const half2v C0={c0,c0},C1={c1,c1},C2={c2,c2},C3={c3,c3},C4={c4,c4},C5={c5,c5};
  const half2v TP={tp,tp}, TN={tn,tn};
#if __has_builtin(__builtin_elementwise_min)
  x = __builtin_elementwise_max(x, TN);
  x = __builtin_elementwise_min(x, TP);
#else
  x.x = x.x > tp ? tp : (x.x < tn ? tn : x.x);
  x.y = x.y > tp ? tp : (x.y < tn ? tn : x.y);
#endif
  half2v t = x*x;
  half2v p = C5*t + C4;
  p = p*t + C3;
  p = p*t + C2;
  p = p*t + C1;
  p = p*t + C0;
  return x*p;
}

// ---------------- ws layout (u32 words) ----------------
// sigma-permuted columns (pair j of a row = original cols c0,c0+1,
// c0 = 16*(j>>3) + 8*((j>>1)&1) + 4*((j>>2)&1) + 2*(j&1)) so the packed C/D
// pair array of the previous MFMA is directly the next B-fragment.
//  [0,512)     A_pk   : iss * Wq^T Wk            [32][16] pairs, perm cols
//  [512,1024)  M_pk   : M = W_ih*OP*WV           perm cols
//  [1024,1536) W_pk   : whh                      perm cols
//  [1536,2048) D_pk   : rows 0-4 = decw, else 0  perm cols
//  [2048,2304) emb_pk : [32][8] pairs; k<5 = embw, k=5 = embb (bias slot), else 0
//  [2304,2320) wv_pk  : iss * Wk^T bq, [grp][8] C/D row-pair order
//  [2320,2352) bM_f   : f32, bM = W_ih*(OP bv + opb) + b_ih + b_hh (natural)
//  [2352,2355) decb_pk: (b0,b1),(b2,b3),(b4,0)
//  [2355,2364) out_pk : row r: (w0,w1),(w2,w3),(w4,0)
__global__ void prep_kernel(const float* __restrict__ inw, const float* __restrict__ inb,
                            const float* __restrict__ opw, const float* __restrict__ opb,
                            const float* __restrict__ wih, const float* __restrict__ bih,
                            const float* __restrict__ bhh, const float* __restrict__ whh,
                            const float* __restrict__ decw, const float* __restrict__ embw,
                            const float* __restrict__ embb,
                            const float* __restrict__ decb, const float* __restrict__ outw,
                            unsigned int* __restrict__ wsu){
  __shared__ float sQ[1024], sK[1024], sV[1024], sOP[1024], sWI[1024];
  __shared__ float sA[1024], sP[1024], sM[1024], sT[32], sWV[32];
  const float ISS = 0.17677669529663689f;   // 1/sqrt(32)
  int t = threadIdx.x;
  sQ[t]  = inw[t];
  sK[t]  = inw[1024 + t];
  sV[t]  = inw[2048 + t];
  sOP[t] = opw[t];
  sWI[t] = wih[t];
  __syncthreads();
  int tx = t & 31, ty = t >> 5;
  float accA = 0.f, accP = 0.f;
  #pragma unroll
  for (int m = 0; m < 32; m++){
    accA += sQ[m*32 + ty] * sK[m*32 + tx];    // Wq[m,ty]*Wk[m,tx]
    accP += sOP[ty*32 + m] * sV[m*32 + tx];   // OP[ty,m]*WV[m,tx]
  }
  sA[ty*32 + tx] = accA;
  sP[ty*32 + tx] = accP;
  if (ty == 0){
    float aw = 0.f;
    #pragma unroll
    for (int m = 0; m < 32; m++) aw += inb[m] * sK[m*32 + tx];   // bq[m]*Wk[m,tx]
    sWV[tx] = aw;
  }
  if (ty == 1){
    float at = opb[tx];
    #pragma unroll
    for (int m = 0; m < 32; m++) at += sOP[tx*32 + m] * inb[64 + m];  // OP[tx,m]*bv[m]
    sT[tx] = at;
  }
  __syncthreads();
  float accM = 0.f;
  #pragma unroll
  for (int m = 0; m < 32; m++) accM += sWI[ty*32 + m] * sP[m*32 + tx];
  sM[ty*32 + tx] = accM;
  if (ty == 2){
    float ab = bih[tx] + bhh[tx];
    #pragma unroll
    for (int m = 0; m < 32; m++) ab += sWI[tx*32 + m] * sT[m];
    ((float*)wsu)[2320 + tx] = ab;
  }
  __syncthreads();
  if (t < 512){
    int r = t >> 4, j = t & 15;
    int c0 = 16*(j>>3) + 8*((j>>1)&1) + 4*((j>>2)&1) + 2*(j&1);   // sigma-perm
    wsu[t]        = pk_rne(ISS*sA[r*32+c0], ISS*sA[r*32+c0+1]);
    wsu[512 + t]  = pk_rne(sM[r*32+c0],  sM[r*32+c0+1]);
    wsu[1024 + t] = pk_rne(whh[r*32+c0], whh[r*32+c0+1]);
    wsu[1536 + t] = (r < 5) ? pk_rne(decw[r*32+c0], decw[r*32+c0+1]) : 0u;
  } else if (t < 768){                     // emb_pk: [32][8] pairs; k5 = embb
    int q = t - 512, j2 = q >> 3, cc = (q & 7)*2;
    float a = (cc   < 5) ? embw[j2*5+cc]   : 0.f;
    float b = (cc+1 < 5) ? embw[j2*5+cc+1] : ((cc+1 == 5) ? embb[j2] : 0.f);
    wsu[2048 + q] = pk_rne(a, b);
  } else if (t < 784){                     // wv_pk in C/D row-pair order, iss-scaled
    int q = t - 768, gg = q >> 3, j = q & 7;
    int r0 = 2*(j&1) + 8*(j>>1) + 4*gg;
    wsu[2304 + q] = pk_rne(ISS*sWV[r0], ISS*sWV[r0+1]);
  } else if (t < 787){                     // decb_pk
    int i = t - 784, c = 2*i;
    float a = decb[c];
    float b = (c+1 < 5) ? decb[c+1] : 0.f;
    wsu[2352 + i] = pk_rne(a, b);
  } else if (t < 796){                     // out_pk: 3 rows x 3 pairs
    int q = t - 787;
    int r = (q >= 6) ? 2 : ((q >= 3) ? 1 : 0);
    int p = q - r*3, c = 2*p;
    float a = outw[r*5 + c];
    float b = (c+1 < 5) ? outw[r*5 + c + 1] : 0.f;
    wsu[2355 + q] = pk_rne(a, b);
  }
}

__device__ __forceinline__ half8 ldfrag(const unsigned int* __restrict__ p){
  U4H8 t; t.u[0]=p[0]; t.u[1]=p[1]; t.u[2]=p[2]; t.u[3]=p[3]; return t.h;
}
__device__ __forceinline__ half8 h8of(const unsigned int* q){
  U4H8 t; t.u[0]=q[0]; t.u[1]=q[1]; t.u[2]=q[2]; t.u[3]=q[3]; return t.h;
}

// 16 f32 bias values for this lane's C-frag rows via 4x float4
__device__ __forceinline__ f32x16 ldbias(const float* __restrict__ p, int grp){
  const float4* b = (const float4*)(p + 4*grp);
  float4 q0 = b[0], q1 = b[2], q2 = b[4], q3 = b[6];
  f32x16 c;
  c[0]=q0.x; c[1]=q0.y; c[2]=q0.z; c[3]=q0.w;
  c[4]=q1.x; c[5]=q1.y; c[6]=q1.z; c[7]=q1.w;
  c[8]=q2.x; c[9]=q2.y; c[10]=q2.z; c[11]=q2.w;
  c[12]=q3.x; c[13]=q3.y; c[14]=q3.z; c[15]=q3.w;
  return c;
}

__global__ __launch_bounds__(BT, 4) void fused_kernel(
    const float* __restrict__ x,
    const unsigned int* __restrict__ wsu,
    const float* __restrict__ outb,
    float* __restrict__ y, long long B)
{
  int tid  = threadIdx.x;
  int lane = tid & 63;
  int col  = lane & 31;
  bool g   = (lane >> 5) != 0;
  int grp  = g ? 1 : 0;
  long long eBase = ((long long)blockIdx.x*(BT/64) + (tid>>6)) * 64;
  if (eBase >= B) return;

  const unsigned int* pA = wsu;
  const unsigned int* pM = wsu + 512;
  const unsigned int* pW = wsu + 1024;
  const unsigned int* pD = wsu + 1536;
  const unsigned int* pE = wsu + 2048;
  const unsigned int* pwv = wsu + 2304;
  const float* bMf = (const float*)(wsu + 2320);
  const unsigned int* pdb  = wsu + 2352;
  const unsigned int* pout = wsu + 2355;

  half8 embA = ldfrag(pE + col*8  + grp*4);
  half8 A1   = ldfrag(pA + col*16 + grp*4), A2 = ldfrag(pA + col*16 + 8 + grp*4);
  half8 M1   = ldfrag(pM + col*16 + grp*4), M2 = ldfrag(pM + col*16 + 8 + grp*4);
  half8 W1   = ldfrag(pW + col*16 + grp*4), W2 = ldfrag(pW + col*16 + 8 + grp*4);
  half8 D1   = ldfrag(pD + col*16 + grp*4), D2 = ldfrag(pD + col*16 + 8 + grp*4);
  half2v wv[8];
  #pragma unroll
  for (int j = 0; j < 8; j++) wv[j] = u2h(pwv[grp*8 + j]);

  f32x16 cb_bM = ldbias(bMf, grp);
  f32x16 z16;
  #pragma unroll
  for (int i = 0; i < 16; i++) z16[i] = 0.f;

  // ---- phase 1: x loads, both tiles (embb rides k=5 with x[k5]=1) ----
  U4H8 xb0[2], xb1[2];
  #pragma unroll
  for (int tt = 0; tt < 2; tt++){
    long long e = eBase + 32*tt + col;
    if (e >= B) e = B - 1;
    const float2* xp = (const float2*)(x + e*10ll);
    float2 p0 = xp[0], p1 = xp[1], p2 = xp[2], p3 = xp[3], p4 = xp[4];
    xb0[tt].u[0] = g ? 0u : h2u(pkrtz(p0.x, p0.y));
    xb0[tt].u[1] = g ? 0u : h2u(pkrtz(p1.x, p1.y));
    xb0[tt].u[2] = g ? 0u : h2u(pkrtz(p2.x, 1.0f));
    xb0[tt].u[3] = 0u;
    xb1[tt].u[0] = g ? 0u : h2u(pkrtz(p2.y, p3.x));
    xb1[tt].u[1] = g ? 0u : h2u(pkrtz(p3.y, p4.x));
    xb1[tt].u[2] = g ? 0u : h2u(pkrtz(p4.y, 1.0f));
    xb1[tt].u[3] = 0u;
  }

  // ---- phase 2: embedding MFMAs (both tiles) + gelu ----
  f32x16 e0D[2], e1D[2];
  #pragma unroll
  for (int tt = 0; tt < 2; tt++){
    e0D[tt] = __builtin_amdgcn_mfma_f32_32x32x16_f16(embA, xb0[tt].h, z16, 0,0,0);
    e1D[tt] = __builtin_amdgcn_mfma_f32_32x32x16_f16(embA, xb1[tt].h, z16, 0,0,0);
  }
  unsigned int epk[2][8], dlpk[2][8];
  #pragma unroll
  for (int tt = 0; tt < 2; tt++){
    #pragma unroll
    for (int i = 0; i < 8; i++){
      half2v e0h = gelu_pk(pkrtz(e0D[tt][2*i], e0D[tt][2*i+1]));
      half2v e1h = gelu_pk(pkrtz(e1D[tt][2*i], e1D[tt][2*i+1]));
      epk[tt][i]  = h2u(e0h);
      dlpk[tt][i] = h2u(e1h - e0h);
    }
  }

  // ---- phase 3: score MFMAs + dots + shfl + softmax ----
  f32x16 gD[2];
  #pragma unroll
  for (int tt = 0; tt < 2; tt++){
    gD[tt] = __builtin_amdgcn_mfma_f32_32x32x16_f16(A1, h8of(dlpk[tt]), z16, 0,0,0);
    gD[tt] = __builtin_amdgcn_mfma_f32_32x32x16_f16(A2, h8of(dlpk[tt]+4), gD[tt], 0,0,0);
  }
  float a01[2], a11[2];
  #pragma unroll
  for (int tt = 0; tt < 2; tt++){
    float t0 = 0.f, t1 = 0.f, dw = 0.f;
    #pragma unroll
    for (int i = 0; i < 8; i++){
      half2v gp = pkrtz(gD[tt][2*i], gD[tt][2*i+1]);
      t0 = fdot2(u2h(epk[tt][i]),  gp, t0);
      t1 = fdot2(u2h(dlpk[tt][i]), gp, t1);
      dw = fdot2(wv[i], u2h(dlpk[tt][i]), dw);
    }
    t0 += __shfl_xor(t0, 32);
    t1 += __shfl_xor(t1, 32);
    dw += __shfl_xor(dw, 32);
    a01[tt] = frcp(1.0f + __expf(-(t0      + dw)));
    a11[tt] = frcp(1.0f + __expf(-(t0 + t1 + dw)));
  }

  // ---- phase 4: c0/c1 in B-layout (packed) ----
  unsigned int c0pk[2][8], c1pk[2][8];
  #pragma unroll
  for (int tt = 0; tt < 2; tt++){
    _Float16 q01 = (_Float16)a01[tt], qda = (_Float16)(a11[tt] - a01[tt]);
    half2v s01 = {q01,q01}, sda = {qda,qda};
    #pragma unroll
    for (int j = 0; j < 8; j++){
      half2v c0 = u2h(dlpk[tt][j])*s01 + u2h(epk[tt][j]);
      half2v c1 = u2h(dlpk[tt][j])*sda + c0;
      c0pk[tt][j] = h2u(c0); c1pk[tt][j] = h2u(c1);
    }
  }

  // ---- phase 5: h1 MFMAs + tanh ----
  f32x16 h1D[2];
  #pragma unroll
  for (int tt = 0; tt < 2; tt++){
    h1D[tt] = __builtin_amdgcn_mfma_f32_32x32x16_f16(M1, h8of(c0pk[tt]), cb_bM, 0,0,0);
    h1D[tt] = __builtin_amdgcn_mfma_f32_32x32x16_f16(M2, h8of(c0pk[tt]+4), h1D[tt], 0,0,0);
  }
  unsigned int h1pk[2][8];
  #pragma unroll
  for (int tt = 0; tt < 2; tt++)
    #pragma unroll
    for (int i = 0; i < 8; i++)
      h1pk[tt][i] = h2u(tanh_pk(pkrtz(h1D[tt][2*i], h1D[tt][2*i+1])));

  // ---- phase 6: h2 MFMAs + tanh ----
  f32x16 h2D[2];
  #pragma unroll
  for (int tt = 0; tt < 2; tt++){
    h2D[tt] = __builtin_amdgcn_mfma_f32_32x32x16_f16(M1, h8of(c1pk[tt]), cb_bM, 0,0,0);
    h2D[tt] = __builtin_amdgcn_mfma_f32_32x32x16_f16(M2, h8of(c1pk[tt]+4), h2D[tt], 0,0,0);
    h2D[tt] = __builtin_amdgcn_mfma_f32_32x32x16_f16(W1, h8of(h1pk[tt]),   h2D[tt], 0,0,0);
    h2D[tt] = __builtin_amdgcn_mfma_f32_32x32x16_f16(W2, h8of(h1pk[tt]+4), h2D[tt], 0,0,0);
  }
  unsigned int h2pk[2][8];
  #pragma unroll
  for (int tt = 0; tt < 2; tt++)
    #pragma unroll
    for (int i = 0; i < 8; i++)
      h2pk[tt][i] = h2u(tanh_pk(pkrtz(h2D[tt][2*i], h2D[tt][2*i+1])));

  // ---- phase 7: decode MFMAs + packed epilogue + store ----
  f32x16 dvD[2];
  #pragma unroll
  for (int tt = 0; tt < 2; tt++){
    dvD[tt] = __builtin_amdgcn_mfma_f32_32x32x16_f16(D1, h8of(h2pk[tt]), z16, 0,0,0);
    dvD[tt] = __builtin_amdgcn_mfma_f32_32x32x16_f16(D2, h8of(h2pk[tt]+4), dvD[tt], 0,0,0);
  }
  #pragma unroll
  for (int tt = 0; tt < 2; tt++){
    float dv4 = __shfl_xor(dvD[tt][0], 32);   // grp1 reg0 = row 4
    half2v dp0 = pkrtz(dvD[tt][0], dvD[tt][1]) + u2h(pdb[0]);
    half2v dp1 = pkrtz(dvD[tt][2], dvD[tt][3]) + u2h(pdb[1]);
    half2v dp2 = pkrtz(dv4,        0.f       ) + u2h(pdb[2]);
    dp0 = gelu_pk(dp0); dp1 = gelu_pk(dp1); dp2 = gelu_pk(dp2);
    float y0 = fdot2(u2h(pout[0]), dp0, fdot2(u2h(pout[1]), dp1, fdot2(u2h(pout[2]), dp2, outb[0])));
    float y1 = fdot2(u2h(pout[3]), dp0, fdot2(u2h(pout[4]), dp1, fdot2(u2h(pout[5]), dp2, outb[1])));
    float y2 = fdot2(u2h(pout[6]), dp0, fdot2(u2h(pout[7]), dp1, fdot2(u2h(pout[8]), dp2, outb[2])));
    long long e = eBase + 32*tt + col;
    if (lane < 32 && e < B){
      float* yp = y + e*3ll;
      yp[0] = y0; yp[1] = y1; yp[2] = y2;
    }
  }
}

extern "C" void kernel_launch(void* const* d_in, const int* in_sizes, int n_in,
                              void* d_out, int out_size, void* d_ws, size_t ws_size,
                              hipStream_t stream){
  const float* x    = (const float*)d_in[0];
  const float* embw = (const float*)d_in[1];
  const float* embb = (const float*)d_in[2];
  const float* inw  = (const float*)d_in[3];
  const float* inb  = (const float*)d_in[4];
  const float* opw  = (const float*)d_in[5];
  const float* opb  = (const float*)d_in[6];
  const float* wih  = (const float*)d_in[7];
  const float* bih  = (const float*)d_in[8];
  const float* whh  = (const float*)d_in[9];
  const float* bhh  = (const float*)d_in[10];
  const float* decw = (const float*)d_in[11];
  const float* decb = (const float*)d_in[12];
  const float* outw = (const float*)d_in[13];
  const float* outb = (const float*)d_in[14];
  float* y = (float*)d_out;
  unsigned int* wsu = (unsigned int*)d_ws;   // 2364 u32 = 9.5 KB

  long long B = in_sizes[0] / 10;            // [B,2,5]
  long long elems_per_block = (BT/64) * 64;  // 256

  prep_kernel<<<1, 1024, 0, stream>>>(inw, inb, opw, opb, wih, bih, bhh,
                                      whh, decw, embw, embb, decb, outw, wsu);
  int grid = (int)((B + elems_per_block - 1)/elems_per_block);
  fused_kernel<<<grid, BT, 0, stream>>>(x, wsu, outb, y, B);
}